// Round 7
// baseline (132.473 us; speedup 1.0000x reference)
//
#include <hip/hip_runtime.h>
#include <cstdint>
#include <cstddef>

#define BATCH 4
#define CIN   512
#define NPIX  1024
#define HEADS 16
#define DH    32
#define DATTN 512
#define O_QKV 1536

typedef unsigned short u16;
typedef __bf16 bf16x4 __attribute__((ext_vector_type(4)));
typedef __bf16 bf16x8 __attribute__((ext_vector_type(8)));
typedef float  f32x4  __attribute__((ext_vector_type(4)));

typedef const __attribute__((address_space(1))) void g1_t;
typedef __attribute__((address_space(3))) void l3_t;

#if defined(__has_builtin)
#if __has_builtin(__builtin_amdgcn_exp2f)
#define EXP2(x) __builtin_amdgcn_exp2f(x)
#endif
#endif
#ifndef EXP2
#define EXP2(x) __expf((x) * 0.6931471805599453f)
#endif

__device__ __forceinline__ u16 f2bf(float f) {
  unsigned u = __float_as_uint(f);
  u += 0x7fffu + ((u >> 16) & 1u);
  return (u16)(u >> 16);
}

// async global->LDS, 16B per lane; lp must be wave-uniform (HW: base + lane*16)
__device__ __forceinline__ void gl_lds16(const void* gp, void* lp) {
  __builtin_amdgcn_global_load_lds((g1_t*)gp, (l3_t*)lp, 16, 0, 0);
}

// ---------------------------------------------------------------------------
// prep_w: convert w_qkv [1536][512] and w_proj [512][512] f32 -> bf16.
// ---------------------------------------------------------------------------
__global__ __launch_bounds__(256) void prep_w(const float* __restrict__ w1,
                                              const float* __restrict__ w2,
                                              u16* __restrict__ o1,
                                              u16* __restrict__ o2) {
  const int idx = blockIdx.x * 256 + threadIdx.x;   // float4 index
  const int n1 = (O_QKV * CIN) >> 2;                // 196608
  float4 v = (idx < n1) ? reinterpret_cast<const float4*>(w1)[idx]
                        : reinterpret_cast<const float4*>(w2)[idx - n1];
  uint2 pk = make_uint2((unsigned)f2bf(v.x) | ((unsigned)f2bf(v.y) << 16),
                        (unsigned)f2bf(v.z) | ((unsigned)f2bf(v.w) << 16));
  if (idx < n1) reinterpret_cast<uint2*>(o1)[idx] = pk;
  else          reinterpret_cast<uint2*>(o2)[idx - n1] = pk;
}

// ---------------------------------------------------------------------------
// prep_x: x [B][C][N] f32 -> xt [B][N][C] bf16 (tiled 64x64 LDS transpose)
// ---------------------------------------------------------------------------
__global__ __launch_bounds__(256) void prep_x(const float* __restrict__ x,
                                              u16* __restrict__ xt) {
  __shared__ float sT[64][65];
  const int t  = threadIdx.x;
  const int n0 = blockIdx.x * 64;
  const int c0 = blockIdx.y * 64;
  const int b  = blockIdx.z;
  const float* xb = x + ((size_t)b * CIN + c0) * NPIX + n0;
#pragma unroll
  for (int i = 0; i < 4; ++i) {
    int r   = i * 16 + (t >> 4);
    int col = (t & 15) << 2;
    float4 v = *reinterpret_cast<const float4*>(&xb[(size_t)r * NPIX + col]);
    sT[r][col + 0] = v.x; sT[r][col + 1] = v.y;
    sT[r][col + 2] = v.z; sT[r][col + 3] = v.w;
  }
  __syncthreads();
#pragma unroll
  for (int i = 0; i < 2; ++i) {
    int nl = t >> 2;
    int ch = (t & 3) + (i << 2);
    u16 tmp[8];
#pragma unroll
    for (int e = 0; e < 8; ++e) tmp[e] = f2bf(sT[(ch << 3) + e][nl]);
    *reinterpret_cast<uint4*>(&xt[((size_t)b * NPIX + n0 + nl) * CIN + c0 + (ch << 3)]) =
        *reinterpret_cast<uint4*>(tmp);
  }
}

// ---------------------------------------------------------------------------
// QKV GEMM (MFMA): M-tile=96 (one head), N-tile=128, BK=64, 4 waves.
// Epilogue: +bias, bf16; q PRE-SCALED by scale*log2e (attn uses exp2 domain).
// qt/kt [b][h][n][32], vt [b][h][d][n].
// ---------------------------------------------------------------------------
__global__ __launch_bounds__(256) void gemm_qkv_mfma(const u16* __restrict__ wq,
                                                     const u16* __restrict__ xt,
                                                     const float* __restrict__ bias,
                                                     u16* __restrict__ qt,
                                                     u16* __restrict__ kt,
                                                     u16* __restrict__ vt) {
  __shared__ __align__(16) u16 sA[96 * 64];
  __shared__ __align__(16) u16 sB[128 * 64];
  const int t  = threadIdx.x;
  const int w  = t >> 6, l = t & 63, g = l >> 4, ln = l & 15;
  const int n0 = blockIdx.x * 128;
  const int h  = blockIdx.y;
  const int b  = blockIdx.z;
  const int wm = w >> 1, wn = w & 1;

  const u16* wbase = wq + (size_t)h * 96 * CIN;
  const u16* xbase = xt + ((size_t)b * NPIX + n0) * CIN;

  f32x4 acc[3][4];
#pragma unroll
  for (int mi = 0; mi < 3; ++mi)
#pragma unroll
    for (int ni = 0; ni < 4; ++ni) acc[mi][ni] = {0.f, 0.f, 0.f, 0.f};

  for (int k0 = 0; k0 < CIN; k0 += 64) {
#pragma unroll
    for (int i = 0; i < 3; ++i) {
      int chunk = i * 256 + (w << 6) + l;
      gl_lds16(wbase + ((size_t)(chunk >> 3)) * CIN + k0 + ((chunk & 7) << 3),
               (char*)sA + i * 4096 + (w << 10));
    }
#pragma unroll
    for (int i = 0; i < 4; ++i) {
      int chunk = i * 256 + (w << 6) + l;
      gl_lds16(xbase + ((size_t)(chunk >> 3)) * CIN + k0 + ((chunk & 7) << 3),
               (char*)sB + i * 4096 + (w << 10));
    }
    __syncthreads();
#pragma unroll
    for (int kk = 0; kk < 64; kk += 32) {
      bf16x8 af[3], bfr[4];
#pragma unroll
      for (int mi = 0; mi < 3; ++mi)
        af[mi] = *reinterpret_cast<const bf16x8*>(&sA[(48 * wm + 16 * mi + ln) * 64 + kk + (g << 3)]);
#pragma unroll
      for (int ni = 0; ni < 4; ++ni)
        bfr[ni] = *reinterpret_cast<const bf16x8*>(&sB[((wn << 6) + (ni << 4) + ln) * 64 + kk + (g << 3)]);
#pragma unroll
      for (int mi = 0; mi < 3; ++mi)
#pragma unroll
        for (int ni = 0; ni < 4; ++ni)
          acc[mi][ni] = __builtin_amdgcn_mfma_f32_16x16x32_bf16(af[mi], bfr[ni], acc[mi][ni], 0, 0, 0);
    }
    __syncthreads();
  }

  const float QSC = 0.17677669529663687f * 1.4426950408889634f;  // scale*log2e
  const float* bh = bias + h * 96;
#pragma unroll
  for (int mi = 0; mi < 3; ++mi) {
    const int sec = 48 * wm + 16 * mi;
    const int rb  = sec + (g << 2);
    const float b0 = bh[rb + 0], b1 = bh[rb + 1], b2 = bh[rb + 2], b3 = bh[rb + 3];
#pragma unroll
    for (int ni = 0; ni < 4; ++ni) {
      const int n = n0 + (wn << 6) + (ni << 4) + ln;
      f32x4 a = acc[mi][ni];
      float v0 = a[0] + b0, v1 = a[1] + b1, v2 = a[2] + b2, v3 = a[3] + b3;
      if (sec < 32) { v0 *= QSC; v1 *= QSC; v2 *= QSC; v3 *= QSC; }
      u16 e0 = f2bf(v0), e1 = f2bf(v1), e2 = f2bf(v2), e3 = f2bf(v3);
      if (sec < 32) {
        const int d = sec + (g << 2);
        uint2 pk = make_uint2((unsigned)e0 | ((unsigned)e1 << 16),
                              (unsigned)e2 | ((unsigned)e3 << 16));
        *reinterpret_cast<uint2*>(&qt[(((size_t)(b * HEADS + h)) * NPIX + n) * DH + d]) = pk;
      } else if (sec < 64) {
        const int d = sec - 32 + (g << 2);
        uint2 pk = make_uint2((unsigned)e0 | ((unsigned)e1 << 16),
                              (unsigned)e2 | ((unsigned)e3 << 16));
        *reinterpret_cast<uint2*>(&kt[(((size_t)(b * HEADS + h)) * NPIX + n) * DH + d]) = pk;
      } else {
        const int d = sec - 64 + (g << 2);
        u16* vp = &vt[(((size_t)(b * HEADS + h)) * DH + d) * NPIX + n];
        vp[0] = e0; vp[NPIX] = e1; vp[2 * NPIX] = e2; vp[3 * NPIX] = e3;
      }
    }
  }
}

// ---------------------------------------------------------------------------
// MFMA flash attention. Grid 1024 = b(4, HIGH bits) x h(16) x i0(16): batch
// siblings (same rel tile) share an XCD (bid%8 invariant to b) -> rel L2 reuse.
// Block: 512 thr, 8 waves = 4 iw (16 i-rows) x 2 jh (j-halves of 512).
// Each wave: 8 j-steps of 64. One __syncthreads per step; K/V double-buffered,
// staged via global_load_lds with pre-swizzled global source (LDS dest linear).
// j-half partials (O, l) merged via LDS at the end (softmax has no max-track).
// K LDS per (buf,jh): [32 packed rows r=j>>1][8 slots 16B], slot ^= (r&7)^((r>>3)&1).
// V LDS per (buf,jh): [32 d][8 slots 16B], slot ^= (d&7).
// sP per wave: [16 rows][8 slots 16B], slot ^= (row&7); b64 half-slot writes.
// ---------------------------------------------------------------------------
__global__ __launch_bounds__(512, 6) void attn_mfma(const u16* __restrict__ qt,
                                                    const u16* __restrict__ kt,
                                                    const u16* __restrict__ vt,
                                                    const float* __restrict__ rel,
                                                    u16* __restrict__ aout) {
  __shared__ __align__(16) u16 sK[2][2][2048];   // [buf][jh][32r][8slot][8]  16KB
  __shared__ __align__(16) u16 sV[2][2][2048];   // [buf][jh][32d][8slot][8]  16KB
  __shared__ __align__(16) u16 sP[8][1024];      // per-wave [16][8slot][8]   16KB

  const int t  = threadIdx.x;
  const int w  = t >> 6, l = t & 63, g = l >> 4, ln = l & 15;
  const int bid = blockIdx.x;
  const int b   = bid >> 8;                 // batch in HIGH bits (XCD-invariant)
  const int rem = bid & 255;
  const int h   = rem >> 4;
  const int i0  = (rem & 15) << 6;
  const int iw  = w & 3;                    // i-segment
  const int jh  = w >> 2;                   // j-half

  const size_t bh = (size_t)(b * HEADS + h);

  // staging mapping (per-thread constant); wave (iw,jh) stages quarter iw of jh
  const int lr = l >> 3, ls = l & 7;
  const int kcl = ls ^ lr ^ (iw & 1);
  const int kj  = (iw << 4) + (lr << 1) + (kcl >> 2);
  const u16* ksrc = kt + (bh * NPIX + (jh << 9) + kj) * DH + ((kcl & 3) << 3);
  const int vcl = ls ^ lr;
  const int vd  = (iw << 3) + lr;
  const u16* vsrc = vt + (bh * DH + vd) * NPIX + (jh << 9) + (vcl << 3);
  char* kdst = (char*)&sK[0][jh][0] + (iw << 10);
  char* vdst = (char*)&sV[0][jh][0] + (iw << 10);

#define STAGE(s_, p_) do {                                          \
    gl_lds16(ksrc + (size_t)(s_) * 2048, kdst + (p_) * 8192);       \
    gl_lds16(vsrc + (size_t)(s_) * 64,   vdst + (p_) * 8192);       \
  } while (0)

  STAGE(0, 0);

  // Q fragment (pre-scaled by scale*log2e): lane -> row i0+16*iw+ln, k=8g..+8
  bf16x8 qf = *reinterpret_cast<const bf16x8*>(
      qt + (bh * NPIX + i0 + (iw << 4) + ln) * DH + (g << 3));

  // rel: rows i0+16iw+4g+v, cols jh*512 + s*64 + 4ln + (0..3)
  const float* relp = rel + ((size_t)h * NPIX + i0 + (iw << 4) + (g << 2)) * NPIX +
                      (jh << 9) + (ln << 2);
  f32x4 relA4[4], relB4[4];
#pragma unroll
  for (int v = 0; v < 4; ++v)
    relA4[v] = *reinterpret_cast<const f32x4*>(relp + (size_t)v * NPIX);

  f32x4 vzero = {0.f, 0.f, 0.f, 0.f};
  f32x4 accO[2] = {vzero, vzero};
  f32x4 l_lane = vzero;

  u16* sPw = &sP[w][0];
  const float LOG2E = 1.4426950408889634f;

  for (int s = 0; s < 8; ++s) {
    const int p = s & 1;
    __syncthreads();                        // buf p staged; buf p^1 free
    if (s < 7) {
      STAGE(s + 1, p ^ 1);
#pragma unroll
      for (int v = 0; v < 4; ++v)
        relB4[v] = *reinterpret_cast<const f32x4*>(relp + (size_t)v * NPIX + ((s + 1) << 6));
    }

    const u16* Kb = &sK[p][jh][0];
    const u16* Vb = &sV[p][jh][0];

    // ---- S' = Q'^T K: fragment jj covers cols j = 4*ln + jj ----
    f32x4 sfr[4];
    __builtin_amdgcn_s_setprio(1);
#pragma unroll
    for (int jj = 0; jj < 4; ++jj) {
      const int r  = (ln << 1) + (jj >> 1);
      const int ks = ((((jj & 1) << 2) | g) ^ (r & 7)) ^ ((r >> 3) & 1);
      bf16x8 kf = *reinterpret_cast<const bf16x8*>(Kb + r * 64 + ks * 8);
      sfr[jj] = __builtin_amdgcn_mfma_f32_16x16x32_bf16(qf, kf, vzero, 0, 0, 0);
    }
    __builtin_amdgcn_s_setprio(0);

    // ---- P = exp2(S' + rel*log2e); swizzled b64 write per row ----
#pragma unroll
    for (int v = 0; v < 4; ++v) {
      float p0 = EXP2(fmaf(relA4[v][0], LOG2E, sfr[0][v]));
      float p1 = EXP2(fmaf(relA4[v][1], LOG2E, sfr[1][v]));
      float p2 = EXP2(fmaf(relA4[v][2], LOG2E, sfr[2][v]));
      float p3 = EXP2(fmaf(relA4[v][3], LOG2E, sfr[3][v]));
      l_lane[v] += (p0 + p1) + (p2 + p3);
      bf16x4 pk;
      pk[0] = (__bf16)p0; pk[1] = (__bf16)p1; pk[2] = (__bf16)p2; pk[3] = (__bf16)p3;
      const int rw = (g << 2) + v;
      *reinterpret_cast<bf16x4*>(
          sPw + rw * 64 + ((((ln >> 1) ^ (rw & 7)) << 3) | ((ln & 1) << 2))) = pk;
    }

    // ---- PV: acc[i][d] += P[i,j] * V[d,j] ----
    __builtin_amdgcn_s_setprio(1);
#pragma unroll
    for (int kc = 0; kc < 2; ++kc) {
      const int lc = (kc << 2) | g;
      bf16x8 pa = *reinterpret_cast<const bf16x8*>(sPw + ln * 64 + ((lc ^ (ln & 7)) << 3));
#pragma unroll
      for (int dc = 0; dc < 2; ++dc) {
        const int d  = (dc << 4) + ln;
        const int vs = lc ^ (d & 7);
        bf16x8 vf = *reinterpret_cast<const bf16x8*>(Vb + d * 64 + vs * 8);
        accO[dc] = __builtin_amdgcn_mfma_f32_16x16x32_bf16(pa, vf, accO[dc], 0, 0, 0);
      }
    }
    __builtin_amdgcn_s_setprio(0);

    if (s < 7) {
#pragma unroll
      for (int v = 0; v < 4; ++v) relA4[v] = relB4[v];
    }
  }
#undef STAGE

  // ---- merge the two j-halves, then finalize (jh==0 waves write out) ----
  __syncthreads();
  float* mrg = (float*)&sK[0][0][0];        // 12.3 KB scratch in old K space
  if (jh == 1) {
    float* mp = mrg + ((size_t)((iw << 6) + l)) * 12;
    *reinterpret_cast<f32x4*>(mp + 0) = accO[0];
    *reinterpret_cast<f32x4*>(mp + 4) = accO[1];
    *reinterpret_cast<f32x4*>(mp + 8) = l_lane;
  }
  __syncthreads();
  if (jh == 0) {
    const float* mp = mrg + ((size_t)((iw << 6) + l)) * 12;
    f32x4 o0 = accO[0] + *reinterpret_cast<const f32x4*>(mp + 0);
    f32x4 o1 = accO[1] + *reinterpret_cast<const f32x4*>(mp + 4);
    f32x4 lv = l_lane + *reinterpret_cast<const f32x4*>(mp + 8);
#pragma unroll
    for (int v = 0; v < 4; ++v) {
      float ls2 = lv[v];
      ls2 += __shfl_xor(ls2, 1);
      ls2 += __shfl_xor(ls2, 2);
      ls2 += __shfl_xor(ls2, 4);
      ls2 += __shfl_xor(ls2, 8);
      const float inv = 1.f / ls2;
      const size_t row = (size_t)b * NPIX + i0 + (iw << 4) + (g << 2) + v;
      aout[row * DATTN + (h << 5) + ln]      = f2bf(o0[v] * inv);
      aout[row * DATTN + (h << 5) + 16 + ln] = f2bf(o1[v] * inv);
    }
  }
}

// ---------------------------------------------------------------------------
// Proj GEMM (MFMA): out[b][o][n] = sum_k Wp[o,k] * A[b][n][k] + bias[o], f32 out.
// ---------------------------------------------------------------------------
__global__ __launch_bounds__(256) void gemm_proj_mfma(const u16* __restrict__ wp,
                                                      const u16* __restrict__ at,
                                                      const float* __restrict__ bias,
                                                      float* __restrict__ out) {
  __shared__ __align__(16) u16 sA[64 * 64];
  __shared__ __align__(16) u16 sB[128 * 64];
  const int t  = threadIdx.x;
  const int w  = t >> 6, l = t & 63, g = l >> 4, ln = l & 15;
  const int n0 = blockIdx.x * 128;
  const int o0 = blockIdx.y * 64;
  const int b  = blockIdx.z;
  const int wm = w >> 1, wn = w & 1;

  const u16* wbase = wp + (size_t)o0 * DATTN;
  const u16* abase = at + ((size_t)b * NPIX + n0) * DATTN;

  f32x4 acc[2][4];
#pragma unroll
  for (int mi = 0; mi < 2; ++mi)
#pragma unroll
    for (int ni = 0; ni < 4; ++ni) acc[mi][ni] = {0.f, 0.f, 0.f, 0.f};

  for (int k0 = 0; k0 < DATTN; k0 += 64) {
#pragma unroll
    for (int i = 0; i < 2; ++i) {
      int chunk = i * 256 + (w << 6) + l;
      gl_lds16(wbase + ((size_t)(chunk >> 3)) * DATTN + k0 + ((chunk & 7) << 3),
               (char*)sA + i * 4096 + (w << 10));
    }
#pragma unroll
    for (int i = 0; i < 4; ++i) {
      int chunk = i * 256 + (w << 6) + l;
      gl_lds16(abase + ((size_t)(chunk >> 3)) * DATTN + k0 + ((chunk & 7) << 3),
               (char*)sB + i * 4096 + (w << 10));
    }
    __syncthreads();
#pragma unroll
    for (int kk = 0; kk < 64; kk += 32) {
      bf16x8 af[2], bfr[4];
#pragma unroll
      for (int mi = 0; mi < 2; ++mi)
        af[mi] = *reinterpret_cast<const bf16x8*>(&sA[((wm << 5) + (mi << 4) + ln) * 64 + kk + (g << 3)]);
#pragma unroll
      for (int ni = 0; ni < 4; ++ni)
        bfr[ni] = *reinterpret_cast<const bf16x8*>(&sB[((wn << 6) + (ni << 4) + ln) * 64 + kk + (g << 3)]);
#pragma unroll
      for (int mi = 0; mi < 2; ++mi)
#pragma unroll
        for (int ni = 0; ni < 4; ++ni)
          acc[mi][ni] = __builtin_amdgcn_mfma_f32_16x16x32_bf16(af[mi], bfr[ni], acc[mi][ni], 0, 0, 0);
    }
    __syncthreads();
  }

#pragma unroll
  for (int mi = 0; mi < 2; ++mi) {
    const int o = o0 + (wm << 5) + (mi << 4) + (g << 2);
    const float b0 = bias[o], b1 = bias[o + 1], b2 = bias[o + 2], b3 = bias[o + 3];
#pragma unroll
    for (int ni = 0; ni < 4; ++ni) {
      const int n = n0 + (wn << 6) + (ni << 4) + ln;
      float* op = &out[((size_t)b * DATTN + o) * NPIX + n];
      op[0]        = acc[mi][ni][0] + b0;
      op[NPIX]     = acc[mi][ni][1] + b1;
      op[2 * NPIX] = acc[mi][ni][2] + b2;
      op[3 * NPIX] = acc[mi][ni][3] + b3;
    }
  }
}

extern "C" void kernel_launch(void* const* d_in, const int* in_sizes, int n_in,
                              void* d_out, int out_size, void* d_ws, size_t ws_size,
                              hipStream_t stream) {
  (void)in_sizes; (void)n_in; (void)out_size; (void)ws_size;
  const float* x      = (const float*)d_in[0];
  const float* w_qkv  = (const float*)d_in[1];
  const float* b_qkv  = (const float*)d_in[2];
  const float* w_proj = (const float*)d_in[3];
  const float* b_proj = (const float*)d_in[4];
  const float* rel    = (const float*)d_in[5];
  float* out = (float*)d_out;

  u16* xt    = (u16*)d_ws;                                   // 4 MB
  u16* wq_bf = xt + (size_t)BATCH * NPIX * CIN;              // 1.5 MB
  u16* wp_bf = wq_bf + (size_t)O_QKV * CIN;                  // 0.5 MB
  u16* qt    = wp_bf + (size_t)DATTN * DATTN;                // 4 MB
  u16* kt    = qt + (size_t)BATCH * HEADS * NPIX * DH;       // 4 MB
  u16* vt    = kt + (size_t)BATCH * HEADS * NPIX * DH;       // 4 MB
  u16* aout  = vt + (size_t)BATCH * HEADS * NPIX * DH;       // 4 MB

  prep_w<<<1024, 256, 0, stream>>>(w_qkv, w_proj, wq_bf, wp_bf);
  prep_x<<<dim3(NPIX / 64, CIN / 64, BATCH), 256, 0, stream>>>(x, xt);
  gemm_qkv_mfma<<<dim3(NPIX / 128, HEADS, BATCH), 256, 0, stream>>>(wq_bf, xt, b_qkv, qt, kt, vt);
  attn_mfma<<<1024, 512, 0, stream>>>(qt, kt, vt, rel, aout);
  gemm_proj_mfma<<<dim3(NPIX / 128, DATTN / 64, BATCH), 256, 0, stream>>>(wp_bf, aout, b_proj, out);
}

// Round 8
// 63.743 us; speedup vs baseline: 2.0782x; 2.0782x over previous
//
#include <hip/hip_runtime.h>
#include <cstdint>
#include <cstddef>

#define BATCH 4
#define CIN   512
#define NPIX  1024
#define HEADS 16
#define DH    32
#define DATTN 512
#define O_QKV 1536

typedef unsigned short u16;
typedef __bf16 bf16x4 __attribute__((ext_vector_type(4)));
typedef __bf16 bf16x8 __attribute__((ext_vector_type(8)));
typedef float  f32x4  __attribute__((ext_vector_type(4)));

typedef const __attribute__((address_space(1))) void g1_t;
typedef __attribute__((address_space(3))) void l3_t;

#if defined(__has_builtin)
#if __has_builtin(__builtin_amdgcn_exp2f)
#define EXP2(x) __builtin_amdgcn_exp2f(x)
#endif
#endif
#ifndef EXP2
#define EXP2(x) __expf((x) * 0.6931471805599453f)
#endif

__device__ __forceinline__ u16 f2bf(float f) {
  unsigned u = __float_as_uint(f);
  u += 0x7fffu + ((u >> 16) & 1u);
  return (u16)(u >> 16);
}

// async global->LDS, 16B per lane; lp must be wave-uniform (HW: base + lane*16)
__device__ __forceinline__ void gl_lds16(const void* gp, void* lp) {
  __builtin_amdgcn_global_load_lds((g1_t*)gp, (l3_t*)lp, 16, 0, 0);
}

// ---------------------------------------------------------------------------
// prep_w: convert w_qkv [1536][512] and w_proj [512][512] f32 -> bf16.
// ---------------------------------------------------------------------------
__global__ __launch_bounds__(256) void prep_w(const float* __restrict__ w1,
                                              const float* __restrict__ w2,
                                              u16* __restrict__ o1,
                                              u16* __restrict__ o2) {
  const int idx = blockIdx.x * 256 + threadIdx.x;   // float4 index
  const int n1 = (O_QKV * CIN) >> 2;                // 196608
  float4 v = (idx < n1) ? reinterpret_cast<const float4*>(w1)[idx]
                        : reinterpret_cast<const float4*>(w2)[idx - n1];
  uint2 pk = make_uint2((unsigned)f2bf(v.x) | ((unsigned)f2bf(v.y) << 16),
                        (unsigned)f2bf(v.z) | ((unsigned)f2bf(v.w) << 16));
  if (idx < n1) reinterpret_cast<uint2*>(o1)[idx] = pk;
  else          reinterpret_cast<uint2*>(o2)[idx - n1] = pk;
}

// ---------------------------------------------------------------------------
// prep_x: x [B][C][N] f32 -> xt [B][N][C] bf16 (tiled 64x64 LDS transpose)
// ---------------------------------------------------------------------------
__global__ __launch_bounds__(256) void prep_x(const float* __restrict__ x,
                                              u16* __restrict__ xt) {
  __shared__ float sT[64][65];
  const int t  = threadIdx.x;
  const int n0 = blockIdx.x * 64;
  const int c0 = blockIdx.y * 64;
  const int b  = blockIdx.z;
  const float* xb = x + ((size_t)b * CIN + c0) * NPIX + n0;
#pragma unroll
  for (int i = 0; i < 4; ++i) {
    int r   = i * 16 + (t >> 4);
    int col = (t & 15) << 2;
    float4 v = *reinterpret_cast<const float4*>(&xb[(size_t)r * NPIX + col]);
    sT[r][col + 0] = v.x; sT[r][col + 1] = v.y;
    sT[r][col + 2] = v.z; sT[r][col + 3] = v.w;
  }
  __syncthreads();
#pragma unroll
  for (int i = 0; i < 2; ++i) {
    int nl = t >> 2;
    int ch = (t & 3) + (i << 2);
    u16 tmp[8];
#pragma unroll
    for (int e = 0; e < 8; ++e) tmp[e] = f2bf(sT[(ch << 3) + e][nl]);
    *reinterpret_cast<uint4*>(&xt[((size_t)b * NPIX + n0 + nl) * CIN + c0 + (ch << 3)]) =
        *reinterpret_cast<uint4*>(tmp);
  }
}

// ---------------------------------------------------------------------------
// QKV GEMM (MFMA): M-tile=96 (one head), N-tile=128, BK=64, 4 waves.
// Epilogue: +bias, bf16; q PRE-SCALED by scale*log2e (attn uses exp2 domain).
// qt/kt [b][h][n][32], vt [b][h][d][n].
// ---------------------------------------------------------------------------
__global__ __launch_bounds__(256) void gemm_qkv_mfma(const u16* __restrict__ wq,
                                                     const u16* __restrict__ xt,
                                                     const float* __restrict__ bias,
                                                     u16* __restrict__ qt,
                                                     u16* __restrict__ kt,
                                                     u16* __restrict__ vt) {
  __shared__ __align__(16) u16 sA[96 * 64];
  __shared__ __align__(16) u16 sB[128 * 64];
  const int t  = threadIdx.x;
  const int w  = t >> 6, l = t & 63, g = l >> 4, ln = l & 15;
  const int n0 = blockIdx.x * 128;
  const int h  = blockIdx.y;
  const int b  = blockIdx.z;
  const int wm = w >> 1, wn = w & 1;

  const u16* wbase = wq + (size_t)h * 96 * CIN;
  const u16* xbase = xt + ((size_t)b * NPIX + n0) * CIN;

  f32x4 acc[3][4];
#pragma unroll
  for (int mi = 0; mi < 3; ++mi)
#pragma unroll
    for (int ni = 0; ni < 4; ++ni) acc[mi][ni] = {0.f, 0.f, 0.f, 0.f};

  for (int k0 = 0; k0 < CIN; k0 += 64) {
#pragma unroll
    for (int i = 0; i < 3; ++i) {
      int chunk = i * 256 + (w << 6) + l;
      gl_lds16(wbase + ((size_t)(chunk >> 3)) * CIN + k0 + ((chunk & 7) << 3),
               (char*)sA + i * 4096 + (w << 10));
    }
#pragma unroll
    for (int i = 0; i < 4; ++i) {
      int chunk = i * 256 + (w << 6) + l;
      gl_lds16(xbase + ((size_t)(chunk >> 3)) * CIN + k0 + ((chunk & 7) << 3),
               (char*)sB + i * 4096 + (w << 10));
    }
    __syncthreads();
#pragma unroll
    for (int kk = 0; kk < 64; kk += 32) {
      bf16x8 af[3], bfr[4];
#pragma unroll
      for (int mi = 0; mi < 3; ++mi)
        af[mi] = *reinterpret_cast<const bf16x8*>(&sA[(48 * wm + 16 * mi + ln) * 64 + kk + (g << 3)]);
#pragma unroll
      for (int ni = 0; ni < 4; ++ni)
        bfr[ni] = *reinterpret_cast<const bf16x8*>(&sB[((wn << 6) + (ni << 4) + ln) * 64 + kk + (g << 3)]);
#pragma unroll
      for (int mi = 0; mi < 3; ++mi)
#pragma unroll
        for (int ni = 0; ni < 4; ++ni)
          acc[mi][ni] = __builtin_amdgcn_mfma_f32_16x16x32_bf16(af[mi], bfr[ni], acc[mi][ni], 0, 0, 0);
    }
    __syncthreads();
  }

  const float QSC = 0.17677669529663687f * 1.4426950408889634f;  // scale*log2e
  const float* bh = bias + h * 96;
#pragma unroll
  for (int mi = 0; mi < 3; ++mi) {
    const int sec = 48 * wm + 16 * mi;
    const int rb  = sec + (g << 2);
    const float b0 = bh[rb + 0], b1 = bh[rb + 1], b2 = bh[rb + 2], b3 = bh[rb + 3];
#pragma unroll
    for (int ni = 0; ni < 4; ++ni) {
      const int n = n0 + (wn << 6) + (ni << 4) + ln;
      f32x4 a = acc[mi][ni];
      float v0 = a[0] + b0, v1 = a[1] + b1, v2 = a[2] + b2, v3 = a[3] + b3;
      if (sec < 32) { v0 *= QSC; v1 *= QSC; v2 *= QSC; v3 *= QSC; }
      u16 e0 = f2bf(v0), e1 = f2bf(v1), e2 = f2bf(v2), e3 = f2bf(v3);
      if (sec < 32) {
        const int d = sec + (g << 2);
        uint2 pk = make_uint2((unsigned)e0 | ((unsigned)e1 << 16),
                              (unsigned)e2 | ((unsigned)e3 << 16));
        *reinterpret_cast<uint2*>(&qt[(((size_t)(b * HEADS + h)) * NPIX + n) * DH + d]) = pk;
      } else if (sec < 64) {
        const int d = sec - 32 + (g << 2);
        uint2 pk = make_uint2((unsigned)e0 | ((unsigned)e1 << 16),
                              (unsigned)e2 | ((unsigned)e3 << 16));
        *reinterpret_cast<uint2*>(&kt[(((size_t)(b * HEADS + h)) * NPIX + n) * DH + d]) = pk;
      } else {
        const int d = sec - 64 + (g << 2);
        u16* vp = &vt[(((size_t)(b * HEADS + h)) * DH + d) * NPIX + n];
        vp[0] = e0; vp[NPIX] = e1; vp[2 * NPIX] = e2; vp[3 * NPIX] = e3;
      }
    }
  }
}

// ---------------------------------------------------------------------------
// MFMA flash attention v8.
// Grid 512: xcd=bid&7, sl=bid>>3; h=(xcd<<1)|(sl>>5), i0=((sl>>1)&15)<<6,
// bp=sl&1 -- bp-siblings (sharing a rel tile) are bid-distance-8 apart: same
// XCD, temporally adjacent -> rel L2 reuse (round-4/5 verified: FETCH 39MB).
// Block: 512 thr, 8 waves = 2 local batches (lb=w>>2) x 4 i-segs (iw=w&3).
// Each wave owns ONE batch (bw=(bp<<1)|lb) and its full j range: 16 j-steps,
// ONE __syncthreads per step (both local batches' K/V staged together).
// K LDS per (buf,lb): [32 packed rows r=j>>1][8 slots 16B], slot^=(r&7)^((r>>3)&1).
// V LDS per (buf,lb): [32 d][8 slots 16B], slot^=(d&7).
// sP per wave: [16 rows][8 slots 16B], slot^=(row&7); b64 half-slot writes.
// LDS 48KB; __launch_bounds__(512,4) (VGPR cap 128 -- NO spill; (512,6) spilled).
// ---------------------------------------------------------------------------
__global__ __launch_bounds__(512, 4) void attn_mfma(const u16* __restrict__ qt,
                                                    const u16* __restrict__ kt,
                                                    const u16* __restrict__ vt,
                                                    const float* __restrict__ rel,
                                                    u16* __restrict__ aout) {
  __shared__ __align__(16) u16 sK[2][2][2048];   // [buf][lb][32r][8slot][8]  16KB
  __shared__ __align__(16) u16 sV[2][2][2048];   // [buf][lb][32d][8slot][8]  16KB
  __shared__ __align__(16) u16 sP[8][1024];      // per-wave [16][8slot][8]   16KB

  const int t  = threadIdx.x;
  const int w  = t >> 6, l = t & 63, g = l >> 4, ln = l & 15;
  const int bid = blockIdx.x;
  const int xcd = bid & 7, sl = bid >> 3;   // sl 0..63
  const int h   = (xcd << 1) | (sl >> 5);
  const int i0  = ((sl >> 1) & 15) << 6;
  const int bp  = sl & 1;                   // batch pair
  const int iw  = w & 3;                    // i-segment
  const int lb  = w >> 2;                   // local batch index
  const int bw  = (bp << 1) | lb;           // this wave's batch

  const size_t bh = (size_t)(bw * HEADS + h);

  // staging (per-thread constant): thread t stages one K chunk + one V chunk
  // of local batch (t>>8), quarter (w&3); c = t&255 -> r=c>>3, slot=c&7.
  const int sc_b  = (bp << 1) | (t >> 8);
  const size_t sc_bh = (size_t)(sc_b * HEADS + h);
  const int sc_cb = t & 255;
  const int sc_r  = sc_cb >> 3;
  const int sc_kc = (sc_cb & 7) ^ (sc_r & 7) ^ ((sc_r >> 3) & 1);  // K logical chunk
  const int sc_vc = (sc_cb & 7) ^ (sc_r & 7);                      // V logical chunk
  const u16* ksrc = kt + (sc_bh * NPIX + ((sc_r << 1) | (sc_kc >> 2))) * DH +
                    ((sc_kc & 3) << 3);
  const u16* vsrc = vt + (sc_bh * DH + sc_r) * NPIX + (sc_vc << 3);
  char* kdst = (char*)&sK[0][t >> 8][0] + (iw << 10);
  char* vdst = (char*)&sV[0][t >> 8][0] + (iw << 10);

#define STAGE(s_, p_) do {                                          \
    gl_lds16(ksrc + (size_t)(s_) * 2048, kdst + (p_) * 8192);       \
    gl_lds16(vsrc + (size_t)(s_) * 64,   vdst + (p_) * 8192);       \
  } while (0)

  STAGE(0, 0);

  // Q fragment (pre-scaled by scale*log2e): lane -> row i0+16*iw+ln, k=8g..+8
  bf16x8 qf = *reinterpret_cast<const bf16x8*>(
      qt + (bh * NPIX + i0 + (iw << 4) + ln) * DH + (g << 3));

  // rel: rows i0+16iw+4g+v, cols s*64 + 4ln + (0..3)
  const float* relp = rel + ((size_t)h * NPIX + i0 + (iw << 4) + (g << 2)) * NPIX +
                      (ln << 2);
  f32x4 relA4[4], relB4[4];
#pragma unroll
  for (int v = 0; v < 4; ++v)
    relA4[v] = *reinterpret_cast<const f32x4*>(relp + (size_t)v * NPIX);

  f32x4 vzero = {0.f, 0.f, 0.f, 0.f};
  f32x4 accO[2] = {vzero, vzero};
  f32x4 l_lane = vzero;

  u16* sPw = &sP[w][0];
  const float LOG2E = 1.4426950408889634f;

  for (int s = 0; s < 16; ++s) {
    const int p = s & 1;
    __syncthreads();                        // buf p staged; buf p^1 free
    if (s < 15) {
      STAGE(s + 1, p ^ 1);
#pragma unroll
      for (int v = 0; v < 4; ++v)
        relB4[v] = *reinterpret_cast<const f32x4*>(relp + (size_t)v * NPIX + ((s + 1) << 6));
    }

    const u16* Kb = &sK[p][lb][0];
    const u16* Vb = &sV[p][lb][0];

    // ---- S' = Q'^T K: fragment jj covers cols j = 4*ln + jj ----
    f32x4 sfr[4];
    __builtin_amdgcn_s_setprio(1);
#pragma unroll
    for (int jj = 0; jj < 4; ++jj) {
      const int r  = (ln << 1) + (jj >> 1);
      const int ks = ((((jj & 1) << 2) | g) ^ (r & 7)) ^ ((r >> 3) & 1);
      bf16x8 kf = *reinterpret_cast<const bf16x8*>(Kb + r * 64 + ks * 8);
      sfr[jj] = __builtin_amdgcn_mfma_f32_16x16x32_bf16(qf, kf, vzero, 0, 0, 0);
    }
    __builtin_amdgcn_s_setprio(0);

    // ---- P = exp2(S' + rel*log2e); swizzled b64 write per row ----
#pragma unroll
    for (int v = 0; v < 4; ++v) {
      float p0 = EXP2(fmaf(relA4[v][0], LOG2E, sfr[0][v]));
      float p1 = EXP2(fmaf(relA4[v][1], LOG2E, sfr[1][v]));
      float p2 = EXP2(fmaf(relA4[v][2], LOG2E, sfr[2][v]));
      float p3 = EXP2(fmaf(relA4[v][3], LOG2E, sfr[3][v]));
      l_lane[v] += (p0 + p1) + (p2 + p3);
      bf16x4 pk;
      pk[0] = (__bf16)p0; pk[1] = (__bf16)p1; pk[2] = (__bf16)p2; pk[3] = (__bf16)p3;
      const int rw = (g << 2) + v;
      *reinterpret_cast<bf16x4*>(
          sPw + rw * 64 + ((((ln >> 1) ^ (rw & 7)) << 3) | ((ln & 1) << 2))) = pk;
    }

    // ---- PV: acc[i][d] += P[i,j] * V[d,j] ----
    __builtin_amdgcn_s_setprio(1);
#pragma unroll
    for (int kc = 0; kc < 2; ++kc) {
      const int lc = (kc << 2) | g;
      bf16x8 pa = *reinterpret_cast<const bf16x8*>(sPw + ln * 64 + ((lc ^ (ln & 7)) << 3));
#pragma unroll
      for (int dc = 0; dc < 2; ++dc) {
        const int d  = (dc << 4) + ln;
        const int vs = lc ^ (d & 7);
        bf16x8 vf = *reinterpret_cast<const bf16x8*>(Vb + d * 64 + vs * 8);
        accO[dc] = __builtin_amdgcn_mfma_f32_16x16x32_bf16(pa, vf, accO[dc], 0, 0, 0);
      }
    }
    __builtin_amdgcn_s_setprio(0);

    if (s < 15) {
#pragma unroll
      for (int v = 0; v < 4; ++v) relA4[v] = relB4[v];
    }
  }
#undef STAGE

  // ---- epilogue: shuffle-reduce l, divide, bf16 write [b][n][c] ----
#pragma unroll
  for (int v = 0; v < 4; ++v) {
    float ls = l_lane[v];
    ls += __shfl_xor(ls, 1);
    ls += __shfl_xor(ls, 2);
    ls += __shfl_xor(ls, 4);
    ls += __shfl_xor(ls, 8);
    const float inv = 1.f / ls;
    const size_t row = (size_t)bw * NPIX + i0 + (iw << 4) + (g << 2) + v;
    aout[row * DATTN + (h << 5) + ln]      = f2bf(accO[0][v] * inv);
    aout[row * DATTN + (h << 5) + 16 + ln] = f2bf(accO[1][v] * inv);
  }
}

// ---------------------------------------------------------------------------
// Proj GEMM (MFMA): out[b][o][n] = sum_k Wp[o,k] * A[b][n][k] + bias[o], f32 out.
// ---------------------------------------------------------------------------
__global__ __launch_bounds__(256) void gemm_proj_mfma(const u16* __restrict__ wp,
                                                      const u16* __restrict__ at,
                                                      const float* __restrict__ bias,
                                                      float* __restrict__ out) {
  __shared__ __align__(16) u16 sA[64 * 64];
  __shared__ __align__(16) u16 sB[128 * 64];
  const int t  = threadIdx.x;
  const int w  = t >> 6, l = t & 63, g = l >> 4, ln = l & 15;
  const int n0 = blockIdx.x * 128;
  const int o0 = blockIdx.y * 64;
  const int b  = blockIdx.z;
  const int wm = w >> 1, wn = w & 1;

  const u16* wbase = wp + (size_t)o0 * DATTN;
  const u16* abase = at + ((size_t)b * NPIX + n0) * DATTN;

  f32x4 acc[2][4];
#pragma unroll
  for (int mi = 0; mi < 2; ++mi)
#pragma unroll
    for (int ni = 0; ni < 4; ++ni) acc[mi][ni] = {0.f, 0.f, 0.f, 0.f};

  for (int k0 = 0; k0 < DATTN; k0 += 64) {
#pragma unroll
    for (int i = 0; i < 2; ++i) {
      int chunk = i * 256 + (w << 6) + l;
      gl_lds16(wbase + ((size_t)(chunk >> 3)) * DATTN + k0 + ((chunk & 7) << 3),
               (char*)sA + i * 4096 + (w << 10));
    }
#pragma unroll
    for (int i = 0; i < 4; ++i) {
      int chunk = i * 256 + (w << 6) + l;
      gl_lds16(abase + ((size_t)(chunk >> 3)) * DATTN + k0 + ((chunk & 7) << 3),
               (char*)sB + i * 4096 + (w << 10));
    }
    __syncthreads();
#pragma unroll
    for (int kk = 0; kk < 64; kk += 32) {
      bf16x8 af[2], bfr[4];
#pragma unroll
      for (int mi = 0; mi < 2; ++mi)
        af[mi] = *reinterpret_cast<const bf16x8*>(&sA[((wm << 5) + (mi << 4) + ln) * 64 + kk + (g << 3)]);
#pragma unroll
      for (int ni = 0; ni < 4; ++ni)
        bfr[ni] = *reinterpret_cast<const bf16x8*>(&sB[((wn << 6) + (ni << 4) + ln) * 64 + kk + (g << 3)]);
#pragma unroll
      for (int mi = 0; mi < 2; ++mi)
#pragma unroll
        for (int ni = 0; ni < 4; ++ni)
          acc[mi][ni] = __builtin_amdgcn_mfma_f32_16x16x32_bf16(af[mi], bfr[ni], acc[mi][ni], 0, 0, 0);
    }
    __syncthreads();
  }

#pragma unroll
  for (int mi = 0; mi < 2; ++mi) {
    const int o = o0 + (wm << 5) + (mi << 4) + (g << 2);
    const float b0 = bias[o], b1 = bias[o + 1], b2 = bias[o + 2], b3 = bias[o + 3];
#pragma unroll
    for (int ni = 0; ni < 4; ++ni) {
      const int n = n0 + (wn << 6) + (ni << 4) + ln;
      float* op = &out[((size_t)b * DATTN + o) * NPIX + n];
      op[0]        = acc[mi][ni][0] + b0;
      op[NPIX]     = acc[mi][ni][1] + b1;
      op[2 * NPIX] = acc[mi][ni][2] + b2;
      op[3 * NPIX] = acc[mi][ni][3] + b3;
    }
  }
}

extern "C" void kernel_launch(void* const* d_in, const int* in_sizes, int n_in,
                              void* d_out, int out_size, void* d_ws, size_t ws_size,
                              hipStream_t stream) {
  (void)in_sizes; (void)n_in; (void)out_size; (void)ws_size;
  const float* x      = (const float*)d_in[0];
  const float* w_qkv  = (const float*)d_in[1];
  const float* b_qkv  = (const float*)d_in[2];
  const float* w_proj = (const float*)d_in[3];
  const float* b_proj = (const float*)d_in[4];
  const float* rel    = (const float*)d_in[5];
  float* out = (float*)d_out;

  u16* xt    = (u16*)d_ws;                                   // 4 MB
  u16* wq_bf = xt + (size_t)BATCH * NPIX * CIN;              // 1.5 MB
  u16* wp_bf = wq_bf + (size_t)O_QKV * CIN;                  // 0.5 MB
  u16* qt    = wp_bf + (size_t)DATTN * DATTN;                // 4 MB
  u16* kt    = qt + (size_t)BATCH * HEADS * NPIX * DH;       // 4 MB
  u16* vt    = kt + (size_t)BATCH * HEADS * NPIX * DH;       // 4 MB
  u16* aout  = vt + (size_t)BATCH * HEADS * NPIX * DH;       // 4 MB

  prep_w<<<1024, 256, 0, stream>>>(w_qkv, w_proj, wq_bf, wp_bf);
  prep_x<<<dim3(NPIX / 64, CIN / 64, BATCH), 256, 0, stream>>>(x, xt);
  gemm_qkv_mfma<<<dim3(NPIX / 128, HEADS, BATCH), 256, 0, stream>>>(wq_bf, xt, b_qkv, qt, kt, vt);
  attn_mfma<<<512, 512, 0, stream>>>(qt, kt, vt, rel, aout);
  gemm_proj_mfma<<<dim3(NPIX / 128, DATTN / 64, BATCH), 256, 0, stream>>>(wp_bf, aout, b_proj, out);
}